// Round 3
// baseline (3785.049 us; speedup 1.0000x reference)
//
#include <hip/hip_runtime.h>
#include <math.h>

#define B_   256
#define NLAB 20000
#define M_   3
#define D_   768
#define T_   5
#define K_   8
#define H_   256
#define DI_  512
#define S_   16
#define R_   16
#define NL_  4
#define KC_  4
#define L_   9          // K+1 tokens
#define NBT  1280       // B*T sequences
#define NROW 11520      // NBT*L flattened rows

// ---------------- helpers ----------------

__device__ __forceinline__ float block_reduce_sum(float v) {
    __shared__ float red[4];
    int lane = threadIdx.x & 63;
    int wid  = threadIdx.x >> 6;
#pragma unroll
    for (int o = 32; o > 0; o >>= 1) v += __shfl_down(v, o);
    if (lane == 0) red[wid] = v;
    __syncthreads();
    int nw = (int)(blockDim.x >> 6);
    float r = 0.f;
#pragma unroll
    for (int i = 0; i < 4; ++i) if (i < nw) r += red[i];
    __syncthreads();
    return r;
}

__device__ __forceinline__ float sigmoidf_(float x) { return 1.f / (1.f + expf(-x)); }
__device__ __forceinline__ float siluf_(float x)    { return x * sigmoidf_(x); }
__device__ __forceinline__ float softplusf_(float x){ return x > 20.f ? x : log1pf(expf(x)); }

// ---------------- kernels ----------------

// softmax over M for modality logits (T x M)
__global__ void k_softmax_w(const float* __restrict__ mlog, float* __restrict__ w) {
    int t = threadIdx.x;
    if (t < T_) {
        float a = mlog[t*M_+0], b = mlog[t*M_+1], c = mlog[t*M_+2];
        float mx = fmaxf(a, fmaxf(b, c));
        float ea = expf(a-mx), eb = expf(b-mx), ec = expf(c-mx);
        float s = ea + eb + ec;
        w[t*M_+0] = ea/s; w[t*M_+1] = eb/s; w[t*M_+2] = ec/s;
    }
}

// qn[(t*B+b)*D + d], uc[b*D + d]
__global__ __launch_bounds__(256) void k_qn_uc(const float* __restrict__ unl,
                                               const float* __restrict__ w,
                                               float* __restrict__ qn,
                                               float* __restrict__ uc) {
    int b = blockIdx.x, tid = threadIdx.x;
    float e[3][3];
#pragma unroll
    for (int c = 0; c < 3; ++c) {
        int d = tid + c*256;
#pragma unroll
        for (int m = 0; m < 3; ++m)
            e[c][m] = unl[((size_t)b*3 + m)*D_ + d];
    }
#pragma unroll
    for (int c = 0; c < 3; ++c)
        uc[(size_t)b*D_ + tid + c*256] = (e[c][0] + e[c][1] + e[c][2]) * (1.f/3.f);
    for (int t = 0; t < T_; ++t) {
        float w0 = w[t*3+0], w1 = w[t*3+1], w2 = w[t*3+2];
        float q[3]; float ss = 0.f;
#pragma unroll
        for (int c = 0; c < 3; ++c) {
            q[c] = w0*e[c][0] + w1*e[c][1] + w2*e[c][2];
            ss += q[c]*q[c];
        }
        float tot = block_reduce_sum(ss);
        float inv = rsqrtf(tot + 1e-8f);
#pragma unroll
        for (int c = 0; c < 3; ++c)
            qn[((size_t)t*B_ + b)*D_ + tid + c*256] = q[c]*inv;
    }
}

// rn[n*T + t] = rsqrt(||kw||^2 + 1e-8)
__global__ __launch_bounds__(256) void k_rn(const float* __restrict__ lab_e,
                                            const float* __restrict__ w,
                                            float* __restrict__ rn) {
    int n = blockIdx.x, tid = threadIdx.x;
    float e[3][3];
#pragma unroll
    for (int c = 0; c < 3; ++c) {
        int d = tid + c*256;
#pragma unroll
        for (int m = 0; m < 3; ++m)
            e[c][m] = lab_e[((size_t)n*3 + m)*D_ + d];
    }
    for (int t = 0; t < T_; ++t) {
        float w0 = w[t*3+0], w1 = w[t*3+1], w2 = w[t*3+2];
        float ss = 0.f;
#pragma unroll
        for (int c = 0; c < 3; ++c) {
            float q = w0*e[c][0] + w1*e[c][1] + w2*e[c][2];
            ss += q*q;
        }
        float tot = block_reduce_sum(ss);
        if (tid == 0) rn[(size_t)n*T_ + t] = rsqrtf(tot + 1e-8f);
    }
}

// sim GEMM over all t: sim[t][b][n] = rn[n,t] * sum_d qn_t[b,d]*(sum_m w[t,m]*lab_e[n,m,d])
// BM=128 (b), BN=128 (n), BK=16; 256 threads, 8x8 microtile; gridDim.z = t
__global__ __launch_bounds__(256) void k_sim_gemm(const float* __restrict__ qn,
                                                  const float* __restrict__ lab_e,
                                                  const float* __restrict__ w,
                                                  const float* __restrict__ rn,
                                                  float* __restrict__ sim) {
    __shared__ float As[16][132];
    __shared__ float Bs[16][132];
    int t  = blockIdx.z;
    int bn = blockIdx.x * 128;
    int bm = blockIdx.y * 128;
    const float* A = qn + (size_t)t*B_*D_;
    float w0 = w[t*3+0], w1 = w[t*3+1], w2 = w[t*3+2];
    int tid = threadIdx.x;
    int tx = tid & 15, ty = tid >> 4;
    int kc = tid & 15, r0 = tid >> 4;
    float acc[8][8] = {};
    for (int k0 = 0; k0 < D_; k0 += 16) {
#pragma unroll
        for (int rr = 0; rr < 8; ++rr) {
            int r = r0 + rr*16;
            As[kc][r] = A[(size_t)(bm + r)*D_ + k0 + kc];
        }
#pragma unroll
        for (int nr = 0; nr < 8; ++nr) {
            int nn = r0 + nr*16;
            int gn = bn + nn;
            float v = 0.f;
            if (gn < NLAB) {
                size_t base = (size_t)gn*(3*D_) + k0 + kc;
                v = w0*lab_e[base] + w1*lab_e[base + D_] + w2*lab_e[base + 2*D_];
            }
            Bs[kc][nn] = v;
        }
        __syncthreads();
#pragma unroll
        for (int k = 0; k < 16; ++k) {
            float ar[8], br[8];
#pragma unroll
            for (int i = 0; i < 8; ++i) ar[i] = As[k][ty*8 + i];
#pragma unroll
            for (int j = 0; j < 8; ++j) br[j] = Bs[k][tx*8 + j];
#pragma unroll
            for (int i = 0; i < 8; ++i)
#pragma unroll
                for (int j = 0; j < 8; ++j)
                    acc[i][j] = fmaf(ar[i], br[j], acc[i][j]);
        }
        __syncthreads();
    }
    float* st = sim + (size_t)t*B_*NLAB;
#pragma unroll
    for (int i = 0; i < 8; ++i) {
        int gm = bm + ty*8 + i;
#pragma unroll
        for (int j = 0; j < 8; ++j) {
            int gn = bn + tx*8 + j;
            if (gn < NLAB)
                st[(size_t)gm*NLAB + gn] = acc[i][j] * rn[(size_t)gn*T_ + t];
        }
    }
}

// per-row top-8 (descending, index tie-break low-first) -> idx[(b*T+t)*K + k]
// grid (B, T)
__global__ __launch_bounds__(256) void k_topk(const float* __restrict__ sim,
                                              int* __restrict__ idx_out) {
    int b = blockIdx.x;
    int t = blockIdx.y;
    int tid = threadIdx.x;
    const float* row = sim + ((size_t)t*B_ + b)*NLAB;
    float tv[8]; int ti[8];
#pragma unroll
    for (int k = 0; k < 8; ++k) { tv[k] = -3e38f; ti[k] = 0x7fffffff; }
    for (int n = tid; n < NLAB; n += 256) {
        float v = row[n];
        if (v > tv[7]) {
            tv[7] = v; ti[7] = n;
#pragma unroll
            for (int k = 7; k > 0; --k) {
                if (tv[k] > tv[k-1]) {
                    float fv = tv[k]; tv[k] = tv[k-1]; tv[k-1] = fv;
                    int fi = ti[k]; ti[k] = ti[k-1]; ti[k-1] = fi;
                }
            }
        }
    }
    __shared__ float sv[2048];
    __shared__ int   si[2048];
    __shared__ float pv[256];
    __shared__ int   pi[256];
    __shared__ int   pp[256];
#pragma unroll
    for (int k = 0; k < 8; ++k) { sv[tid*8+k] = tv[k]; si[tid*8+k] = ti[k]; }
    __syncthreads();
    for (int r = 0; r < 8; ++r) {
        float bv = -3e38f; int bi = 0x7fffffff; int bp = 0;
#pragma unroll
        for (int k = 0; k < 8; ++k) {
            int p = tid*8 + k;
            float v = sv[p]; int ii = si[p];
            if (v > bv || (v == bv && ii < bi)) { bv = v; bi = ii; bp = p; }
        }
        pv[tid] = bv; pi[tid] = bi; pp[tid] = bp;
        __syncthreads();
        for (int off = 128; off > 0; off >>= 1) {
            if (tid < off) {
                if (pv[tid+off] > pv[tid] || (pv[tid+off] == pv[tid] && pi[tid+off] < pi[tid])) {
                    pv[tid] = pv[tid+off]; pi[tid] = pi[tid+off]; pp[tid] = pp[tid+off];
                }
            }
            __syncthreads();
        }
        if (tid == 0) {
            idx_out[((size_t)b*T_ + t)*K_ + r] = pi[0];
            sv[pp[0]] = -3e38f;
        }
        __syncthreads();
    }
}

// build tokens: toks[(bt*9 + l)*769 + :]
__global__ __launch_bounds__(256) void k_toks(const float* __restrict__ lab_e,
                                              const float* __restrict__ lab_t,
                                              const float* __restrict__ uc,
                                              const int* __restrict__ idx,
                                              float* __restrict__ toks) {
    int g = blockIdx.x;            // 0..NROW-1
    int bt = g / L_, l = g % L_;
    int b = bt / T_, t = bt % T_;
    float* out = toks + (size_t)g*(D_+1);
    if (l < K_) {
        int n = idx[(size_t)bt*K_ + l];
        for (int d = threadIdx.x; d < D_; d += 256) {
            size_t base = (size_t)n*(3*D_) + d;
            out[d] = (lab_e[base] + lab_e[base + D_] + lab_e[base + 2*D_]) * (1.f/3.f);
        }
        if (threadIdx.x == 0) out[D_] = lab_t[(size_t)n*T_ + t];
    } else {
        for (int d = threadIdx.x; d < D_; d += 256)
            out[d] = uc[(size_t)b*D_ + d];
        if (threadIdx.x == 0) out[D_] = 0.f;
    }
}

// tiled fp32 GEMM: C(MxN) (+)= A(MxK) * B(KxN) (+ bias)
// BM=128, BN=128, BK=16; 256 threads, 8x8 microtile
template<bool ADD, bool BIAS>
__global__ __launch_bounds__(256) void k_sgemm2(const float* __restrict__ A,
                                                const float* __restrict__ Bm,
                                                const float* __restrict__ bias,
                                                float* __restrict__ C,
                                                int M, int N, int Kd) {
    __shared__ float As[16][132];
    __shared__ float Bs[16][132];
    int bn = blockIdx.x * 128;
    int bm = blockIdx.y * 128;
    int tid = threadIdx.x;
    int tx = tid & 15, ty = tid >> 4;
    int kc = tid & 15, r0 = tid >> 4;
    int nn = tid & 127;
    int kk0 = tid >> 7;        // 0 or 1
    float acc[8][8] = {};
    for (int k0 = 0; k0 < Kd; k0 += 16) {
        bool kok = (k0 + kc) < Kd;
#pragma unroll
        for (int rr = 0; rr < 8; ++rr) {
            int r = r0 + rr*16;
            int gm = bm + r;
            As[kc][r] = (kok && gm < M) ? A[(size_t)gm*Kd + k0 + kc] : 0.f;
        }
#pragma unroll
        for (int kki = 0; kki < 8; ++kki) {
            int kk = kk0 + kki*2;
            int gk = k0 + kk, gn = bn + nn;
            Bs[kk][nn] = (gk < Kd && gn < N) ? Bm[(size_t)gk*N + gn] : 0.f;
        }
        __syncthreads();
#pragma unroll
        for (int k = 0; k < 16; ++k) {
            float ar[8], br[8];
#pragma unroll
            for (int i = 0; i < 8; ++i) ar[i] = As[k][ty*8 + i];
#pragma unroll
            for (int j = 0; j < 8; ++j) br[j] = Bs[k][tx*8 + j];
#pragma unroll
            for (int i = 0; i < 8; ++i)
#pragma unroll
                for (int j = 0; j < 8; ++j)
                    acc[i][j] = fmaf(ar[i], br[j], acc[i][j]);
        }
        __syncthreads();
    }
#pragma unroll
    for (int i = 0; i < 8; ++i) {
        int gm = bm + ty*8 + i;
        if (gm >= M) continue;
#pragma unroll
        for (int j = 0; j < 8; ++j) {
            int gn = bn + tx*8 + j;
            if (gn >= N) continue;
            float v = acc[i][j];
            if (BIAS) v += bias[gn];
            size_t o = (size_t)gm*N + gn;
            if (ADD) C[o] += v; else C[o] = v;
        }
    }
}

// layer norm per row of H=256
__global__ __launch_bounds__(256) void k_ln(const float* __restrict__ x,
                                            const float* __restrict__ g,
                                            const float* __restrict__ b,
                                            float* __restrict__ xn) {
    int row = blockIdx.x, tid = threadIdx.x;
    float v = x[(size_t)row*H_ + tid];
    float mean = block_reduce_sum(v) * (1.f/H_);
    float d = v - mean;
    float var = block_reduce_sum(d*d) * (1.f/H_);
    xn[(size_t)row*H_ + tid] = d * rsqrtf(var + 1e-5f) * g[tid] + b[tid];
}

// causal depthwise conv (KC=4) + silu ; xc from first half of xz
__global__ __launch_bounds__(256) void k_conv(const float* __restrict__ xz,
                                              const float* __restrict__ cw,
                                              const float* __restrict__ cb,
                                              float* __restrict__ xc2) {
    int gid = blockIdx.x*256 + threadIdx.x;
    if (gid >= NBT*DI_) return;
    int n = gid / DI_, d = gid % DI_;
    float w0 = cw[d*4+0], w1 = cw[d*4+1], w2 = cw[d*4+2], w3 = cw[d*4+3];
    float bb = cb[d];
    const float* src = xz + (size_t)n*L_*(2*DI_) + d;
    float* dst = xc2 + (size_t)n*L_*DI_ + d;
    float x0 = 0.f, x1 = 0.f, x2 = 0.f;
#pragma unroll
    for (int l = 0; l < L_; ++l) {
        float x3 = src[(size_t)l*(2*DI_)];
        float s = bb + w0*x0 + w1*x1 + w2*x2 + w3*x3;
        dst[(size_t)l*DI_] = siluf_(s);
        x0 = x1; x1 = x2; x2 = x3;
    }
}

// dbl = xc2 @ Wx  (NROW x 48)
__global__ __launch_bounds__(256) void k_dbl(const float* __restrict__ xc2,
                                             const float* __restrict__ Wx,
                                             float* __restrict__ dbl) {
    int gid = blockIdx.x*256 + threadIdx.x;
    if (gid >= NROW*48) return;
    int row = gid / 48, j = gid % 48;
    const float* a = xc2 + (size_t)row*DI_;
    float s0 = 0.f, s1 = 0.f, s2 = 0.f, s3 = 0.f;
    for (int k = 0; k < DI_; k += 4) {
        s0 = fmaf(a[k+0], Wx[(size_t)(k+0)*48 + j], s0);
        s1 = fmaf(a[k+1], Wx[(size_t)(k+1)*48 + j], s1);
        s2 = fmaf(a[k+2], Wx[(size_t)(k+2)*48 + j], s2);
        s3 = fmaf(a[k+3], Wx[(size_t)(k+3)*48 + j], s3);
    }
    dbl[gid] = ((s0 + s1) + (s2 + s3));
}

// dt = softplus(dbl[:, :16] @ Wdt + bdt)   (NROW x 512)
__global__ __launch_bounds__(256) void k_dt(const float* __restrict__ dbl,
                                            const float* __restrict__ Wdt,
                                            const float* __restrict__ bdt,
                                            float* __restrict__ dt) {
    int gid = blockIdx.x*256 + threadIdx.x;
    if (gid >= NROW*DI_) return;
    int row = gid >> 9, d = gid & (DI_-1);
    const float* p = dbl + (size_t)row*48;
    float s = bdt[d];
#pragma unroll
    for (int r = 0; r < R_; ++r) s = fmaf(p[r], Wdt[(size_t)r*DI_ + d], s);
    dt[gid] = softplusf_(s);
}

// selective scan + skip + gate: y[row,d] = (sum_s hs*Cm + Dp*xc) * silu(z)
__global__ __launch_bounds__(256) void k_scan(const float* __restrict__ dtb,
                                              const float* __restrict__ xc2,
                                              const float* __restrict__ xz,
                                              const float* __restrict__ dbl,
                                              const float* __restrict__ A_log,
                                              const float* __restrict__ Dp,
                                              float* __restrict__ y) {
    int gid = blockIdx.x*256 + threadIdx.x;
    if (gid >= NBT*DI_) return;
    int n = gid >> 9, d = gid & (DI_-1);
    float a[S_];
#pragma unroll
    for (int s = 0; s < S_; ++s) a[s] = -expf(A_log[(size_t)d*S_ + s]);
    float dp = Dp[d];
    float h[S_];
#pragma unroll
    for (int s = 0; s < S_; ++s) h[s] = 0.f;
    for (int l = 0; l < L_; ++l) {
        size_t row = (size_t)n*L_ + l;
        float dtv = dtb[row*DI_ + d];
        float xcv = xc2[row*DI_ + d];
        float zv  = xz[row*(2*DI_) + DI_ + d];
        const float* q = dbl + row*48;
        float accv = 0.f;
#pragma unroll
        for (int s = 0; s < S_; ++s) {
            float Bv = q[16 + s], Cv = q[32 + s];
            h[s] = expf(dtv*a[s])*h[s] + dtv*Bv*xcv;
            accv = fmaf(h[s], Cv, accv);
        }
        y[row*DI_ + d] = (accv + dp*xcv) * siluf_(zv);
    }
}

// head: out[n] = relu(x[n,8,:] @ W1 + b1) @ W2 + b2
__global__ __launch_bounds__(128) void k_head(const float* __restrict__ x,
                                              const float* __restrict__ W1,
                                              const float* __restrict__ b1,
                                              const float* __restrict__ W2,
                                              const float* __restrict__ b2,
                                              float* __restrict__ out) {
    int n = blockIdx.x, tid = threadIdx.x;
    __shared__ float ms[H_];
    const float* src = x + ((size_t)n*L_ + (L_-1))*H_;
    ms[tid] = src[tid];
    ms[tid+128] = src[tid+128];
    __syncthreads();
    float s = b1[tid];
#pragma unroll 8
    for (int k = 0; k < H_; ++k) s = fmaf(ms[k], W1[(size_t)k*128 + tid], s);
    float h = fmaxf(s, 0.f);
    float p = h * W2[tid];
    float tot = block_reduce_sum(p);
    if (tid == 0) out[n] = tot + b2[0];
}

// ---------------- launch ----------------

extern "C" void kernel_launch(void* const* d_in, const int* in_sizes, int n_in,
                              void* d_out, int out_size, void* d_ws, size_t ws_size,
                              hipStream_t stream) {
    const float* unl   = (const float*)d_in[0];
    const float* lab_e = (const float*)d_in[1];
    const float* lab_t = (const float*)d_in[2];
    const float* mlog  = (const float*)d_in[3];
    const float* Wp    = (const float*)d_in[4];
    const float* bp    = (const float*)d_in[5];
    const float* ln_g  = (const float*)d_in[6];
    const float* ln_b  = (const float*)d_in[7];
    const float* Win   = (const float*)d_in[8];
    const float* conv_w= (const float*)d_in[9];
    const float* conv_b= (const float*)d_in[10];
    const float* Wx    = (const float*)d_in[11];
    const float* Wdt   = (const float*)d_in[12];
    const float* bdt   = (const float*)d_in[13];
    const float* A_log = (const float*)d_in[14];
    const float* Dp    = (const float*)d_in[15];
    const float* Wout  = (const float*)d_in[16];
    const float* W1    = (const float*)d_in[17];
    const float* b1    = (const float*)d_in[18];
    const float* W2    = (const float*)d_in[19];
    const float* b2    = (const float*)d_in[20];

    float* ws   = (float*)d_ws;
    float* w    = ws;                          // 16
    int*   idx  = (int*)(ws + 16);             // 10240
    float* uc   = ws + 16 + 10240;             // B*D = 196608
    float* base = uc + (size_t)B_*D_;
    // phase 1 (overlaps phase 2 region)
    float* qn   = base;                        // T*B*D = 983040
    float* rn   = qn + (size_t)T_*B_*D_;       // NLAB*T = 100000
    float* sim  = rn + (size_t)NLAB*T_;        // T*B*NLAB = 25,600,000
    // phase 2
    float* toks = base;                        // NROW*769
    float* xa   = toks + (size_t)NROW*(D_+1);  // NROW*256
    float* xb   = xa + (size_t)NROW*H_;        // NROW*256
    float* xz   = xb + (size_t)NROW*H_;        // NROW*1024
    float* xc2  = xz + (size_t)NROW*(2*DI_);   // NROW*512
    float* dbl  = xc2 + (size_t)NROW*DI_;      // NROW*48
    float* dtb  = dbl + (size_t)NROW*48;       // NROW*512
    float* y    = dtb + (size_t)NROW*DI_;      // NROW*512

    k_softmax_w<<<1, 64, 0, stream>>>(mlog, w);
    k_qn_uc<<<B_, 256, 0, stream>>>(unl, w, qn, uc);
    k_rn<<<NLAB, 256, 0, stream>>>(lab_e, w, rn);
    {
        dim3 g((NLAB + 127) / 128, B_ / 128, T_);
        k_sim_gemm<<<g, 256, 0, stream>>>(qn, lab_e, w, rn, sim);
    }
    {
        dim3 g(B_, T_);
        k_topk<<<g, 256, 0, stream>>>(sim, idx);
    }
    k_toks<<<NROW, 256, 0, stream>>>(lab_e, lab_t, uc, idx, toks);
    {
        dim3 g(H_/128, NROW/128);
        k_sgemm2<false,true><<<g, 256, 0, stream>>>(toks, Wp, bp, xa, NROW, H_, D_+1);
    }
    // reference's residual is around the POST-LN tensor:
    //   xn = LN(x); x = xn + f(xn) @ Wout   (pre-norm x is discarded)
    float* cur = xa;
    float* oth = xb;
    for (int i = 0; i < NL_; ++i) {
        k_ln<<<NROW, 256, 0, stream>>>(cur, ln_g + (size_t)i*H_, ln_b + (size_t)i*H_, oth);
        {
            dim3 g((2*DI_)/128, NROW/128);
            k_sgemm2<false,false><<<g, 256, 0, stream>>>(oth, Win + (size_t)i*H_*(2*DI_), nullptr, xz, NROW, 2*DI_, H_);
        }
        k_conv<<<(NBT*DI_ + 255)/256, 256, 0, stream>>>(xz, conv_w + (size_t)i*DI_*KC_, conv_b + (size_t)i*DI_, xc2);
        k_dbl<<<(NROW*48 + 255)/256, 256, 0, stream>>>(xc2, Wx + (size_t)i*DI_*48, dbl);
        k_dt<<<(NROW*DI_ + 255)/256, 256, 0, stream>>>(dbl, Wdt + (size_t)i*R_*DI_, bdt + (size_t)i*DI_, dtb);
        k_scan<<<(NBT*DI_ + 255)/256, 256, 0, stream>>>(dtb, xc2, xz, dbl, A_log + (size_t)i*DI_*S_, Dp + (size_t)i*DI_, y);
        {
            dim3 g(H_/128, NROW/128);
            k_sgemm2<true,false><<<g, 256, 0, stream>>>(y, Wout + (size_t)i*DI_*H_, nullptr, oth, NROW, H_, DI_);
        }
        float* tmp = cur; cur = oth; oth = tmp;
    }
    k_head<<<NBT, 128, 0, stream>>>(cur, W1, b1, W2, b2, (float*)d_out);
}

// Round 4
// 2645.069 us; speedup vs baseline: 1.4310x; 1.4310x over previous
//
#include <hip/hip_runtime.h>
#include <math.h>

#define B_   256
#define NLAB 20000
#define M_   3
#define D_   768
#define T_   5
#define K_   8
#define H_   256
#define DI_  512
#define S_   16
#define R_   16
#define NL_  4
#define KC_  4
#define L_   9          // K+1 tokens
#define NBT  1280       // B*T sequences
#define NROW 11520      // NBT*L flattened rows

typedef __attribute__((ext_vector_type(8))) short bf16x8;
typedef __attribute__((ext_vector_type(4))) float floatx4;

// ---------------- helpers ----------------

__device__ __forceinline__ float block_reduce_sum(float v) {
    __shared__ float red[4];
    int lane = threadIdx.x & 63;
    int wid  = threadIdx.x >> 6;
#pragma unroll
    for (int o = 32; o > 0; o >>= 1) v += __shfl_down(v, o);
    if (lane == 0) red[wid] = v;
    __syncthreads();
    int nw = (int)(blockDim.x >> 6);
    float r = 0.f;
#pragma unroll
    for (int i = 0; i < 4; ++i) if (i < nw) r += red[i];
    __syncthreads();
    return r;
}

__device__ __forceinline__ float sigmoidf_(float x) { return 1.f / (1.f + expf(-x)); }
__device__ __forceinline__ float siluf_(float x)    { return x * sigmoidf_(x); }
__device__ __forceinline__ float softplusf_(float x){ return x > 20.f ? x : log1pf(expf(x)); }

// round-to-nearest-even fp32 -> bf16 bits
__device__ __forceinline__ unsigned short f2bf(float x) {
    unsigned u = __float_as_uint(x);
    unsigned r = (u + 0x7fffu + ((u >> 16) & 1u)) >> 16;
    return (unsigned short)r;
}
__device__ __forceinline__ float bf2f(unsigned short h) {
    return __uint_as_float(((unsigned)h) << 16);
}

// ---------------- kernels ----------------

// softmax over M for modality logits (T x M)
__global__ void k_softmax_w(const float* __restrict__ mlog, float* __restrict__ w) {
    int t = threadIdx.x;
    if (t < T_) {
        float a = mlog[t*M_+0], b = mlog[t*M_+1], c = mlog[t*M_+2];
        float mx = fmaxf(a, fmaxf(b, c));
        float ea = expf(a-mx), eb = expf(b-mx), ec = expf(c-mx);
        float s = ea + eb + ec;
        w[t*M_+0] = ea/s; w[t*M_+1] = eb/s; w[t*M_+2] = ec/s;
    }
}

// qn[(t*B+b)*D + d], uc[b*D + d]
__global__ __launch_bounds__(256) void k_qn_uc(const float* __restrict__ unl,
                                               const float* __restrict__ w,
                                               float* __restrict__ qn,
                                               float* __restrict__ uc) {
    int b = blockIdx.x, tid = threadIdx.x;
    float e[3][3];
#pragma unroll
    for (int c = 0; c < 3; ++c) {
        int d = tid + c*256;
#pragma unroll
        for (int m = 0; m < 3; ++m)
            e[c][m] = unl[((size_t)b*3 + m)*D_ + d];
    }
#pragma unroll
    for (int c = 0; c < 3; ++c)
        uc[(size_t)b*D_ + tid + c*256] = (e[c][0] + e[c][1] + e[c][2]) * (1.f/3.f);
    for (int t = 0; t < T_; ++t) {
        float w0 = w[t*3+0], w1 = w[t*3+1], w2 = w[t*3+2];
        float q[3]; float ss = 0.f;
#pragma unroll
        for (int c = 0; c < 3; ++c) {
            q[c] = w0*e[c][0] + w1*e[c][1] + w2*e[c][2];
            ss += q[c]*q[c];
        }
        float tot = block_reduce_sum(ss);
        float inv = rsqrtf(tot + 1e-8f);
#pragma unroll
        for (int c = 0; c < 3; ++c)
            qn[((size_t)t*B_ + b)*D_ + tid + c*256] = q[c]*inv;
    }
}

// rn[n*T + t] = rsqrt(||kw||^2 + 1e-8)
__global__ __launch_bounds__(256) void k_rn(const float* __restrict__ lab_e,
                                            const float* __restrict__ w,
                                            float* __restrict__ rn) {
    int n = blockIdx.x, tid = threadIdx.x;
    float e[3][3];
#pragma unroll
    for (int c = 0; c < 3; ++c) {
        int d = tid + c*256;
#pragma unroll
        for (int m = 0; m < 3; ++m)
            e[c][m] = lab_e[((size_t)n*3 + m)*D_ + d];
    }
    for (int t = 0; t < T_; ++t) {
        float w0 = w[t*3+0], w1 = w[t*3+1], w2 = w[t*3+2];
        float ss = 0.f;
#pragma unroll
        for (int c = 0; c < 3; ++c) {
            float q = w0*e[c][0] + w1*e[c][1] + w2*e[c][2];
            ss += q*q;
        }
        float tot = block_reduce_sum(ss);
        if (tid == 0) rn[(size_t)n*T_ + t] = rsqrtf(tot + 1e-8f);
    }
}

// split-bf16 MFMA sim GEMM:
// sim[t][b][n] = rn[n,t] * sum_d qn_t[b,d] * (sum_m w[t,m]*lab_e[n,m,d])
// 3-pass Ozaki: a=ah+al, b=bh+bl; C ~= ah*bh + al*bh + ah*bl (fp32 MFMA acc)
// tile 128x128, BK=32; 4 waves, each 64x64 via 4x4 mfma_f32_16x16x32_bf16
// grid: x = t*2 + m-block (10, fastest -> LLC reuse of lab_e slice), y = n-block (157)
__global__ __launch_bounds__(256) void k_simf(const float* __restrict__ qn,
                                              const float* __restrict__ lab_e,
                                              const float* __restrict__ w,
                                              const float* __restrict__ rn,
                                              float* __restrict__ sim) {
    __shared__ unsigned short Ah[128*40], Al[128*40], Bh[128*40], Bl[128*40];
    int t  = blockIdx.x >> 1;
    int bm = (blockIdx.x & 1) * 128;
    int bn = blockIdx.y * 128;
    const float* A = qn + (size_t)t*B_*D_;
    float w0 = w[t*3+0], w1 = w[t*3+1], w2 = w[t*3+2];
    int tid = threadIdx.x;
    int lane = tid & 63, wv = tid >> 6;
    int mbase = (wv & 1)*64, nbase = (wv >> 1)*64;
    int fr = lane & 15, kg = lane >> 4;
    floatx4 acc[4][4];
#pragma unroll
    for (int mi = 0; mi < 4; ++mi)
#pragma unroll
        for (int ni = 0; ni < 4; ++ni)
            acc[mi][ni] = (floatx4){0.f, 0.f, 0.f, 0.f};

    for (int k0 = 0; k0 < D_; k0 += 32) {
        // stage A (128 x 32 fp32 -> hi/lo bf16)
#pragma unroll
        for (int f = 0; f < 4; ++f) {
            int v = f*256 + tid;
            int r = v >> 3, kq = v & 7;
            float4 av = *(const float4*)(A + (size_t)(bm + r)*D_ + k0 + kq*4);
            ushort4 h, l;
            h.x = f2bf(av.x); l.x = f2bf(av.x - bf2f(h.x));
            h.y = f2bf(av.y); l.y = f2bf(av.y - bf2f(h.y));
            h.z = f2bf(av.z); l.z = f2bf(av.z - bf2f(h.z));
            h.w = f2bf(av.w); l.w = f2bf(av.w - bf2f(h.w));
            int off = r*40 + kq*4;
            *(ushort4*)(Ah + off) = h;
            *(ushort4*)(Al + off) = l;
        }
        // stage B: weighted lab_e (128 n x 32 k) -> hi/lo bf16
#pragma unroll
        for (int f = 0; f < 4; ++f) {
            int v = f*256 + tid;
            int r = v >> 3, kq = v & 7;
            int gn = bn + r;
            float4 s = make_float4(0.f, 0.f, 0.f, 0.f);
            if (gn < NLAB) {
                const float* bp = lab_e + (size_t)gn*(3*D_) + k0 + kq*4;
                float4 e0 = *(const float4*)(bp);
                float4 e1 = *(const float4*)(bp + D_);
                float4 e2 = *(const float4*)(bp + 2*D_);
                s.x = w0*e0.x + w1*e1.x + w2*e2.x;
                s.y = w0*e0.y + w1*e1.y + w2*e2.y;
                s.z = w0*e0.z + w1*e1.z + w2*e2.z;
                s.w = w0*e0.w + w1*e1.w + w2*e2.w;
            }
            ushort4 h, l;
            h.x = f2bf(s.x); l.x = f2bf(s.x - bf2f(h.x));
            h.y = f2bf(s.y); l.y = f2bf(s.y - bf2f(h.y));
            h.z = f2bf(s.z); l.z = f2bf(s.z - bf2f(h.z));
            h.w = f2bf(s.w); l.w = f2bf(s.w - bf2f(h.w));
            int off = r*40 + kq*4;
            *(ushort4*)(Bh + off) = h;
            *(ushort4*)(Bl + off) = l;
        }
        __syncthreads();

        bf16x8 bhf[4], blf[4];
#pragma unroll
        for (int ni = 0; ni < 4; ++ni) {
            int off = (nbase + ni*16 + fr)*40 + kg*8;
            bhf[ni] = *(const bf16x8*)(Bh + off);
            blf[ni] = *(const bf16x8*)(Bl + off);
        }
#pragma unroll
        for (int mi = 0; mi < 4; ++mi) {
            int off = (mbase + mi*16 + fr)*40 + kg*8;
            bf16x8 ahf = *(const bf16x8*)(Ah + off);
            bf16x8 alf = *(const bf16x8*)(Al + off);
#pragma unroll
            for (int ni = 0; ni < 4; ++ni) {
                floatx4 c = acc[mi][ni];
                c = __builtin_amdgcn_mfma_f32_16x16x32_bf16(ahf, bhf[ni], c, 0, 0, 0);
                c = __builtin_amdgcn_mfma_f32_16x16x32_bf16(alf, bhf[ni], c, 0, 0, 0);
                c = __builtin_amdgcn_mfma_f32_16x16x32_bf16(ahf, blf[ni], c, 0, 0, 0);
                acc[mi][ni] = c;
            }
        }
        __syncthreads();
    }
    // epilogue: C/D layout col=lane&15, row=(lane>>4)*4+reg
    float* st = sim + (size_t)t*B_*NLAB;
#pragma unroll
    for (int mi = 0; mi < 4; ++mi) {
        int m = bm + mbase + mi*16 + kg*4;
#pragma unroll
        for (int ni = 0; ni < 4; ++ni) {
            int n = bn + nbase + ni*16 + fr;
            if (n < NLAB) {
                float rv = rn[(size_t)n*T_ + t];
#pragma unroll
                for (int r = 0; r < 4; ++r)
                    st[(size_t)(m + r)*NLAB + n] = acc[mi][ni][r] * rv;
            }
        }
    }
}

// per-row top-8 (descending, index tie-break low-first) -> idx[(b*T+t)*K + k]
// grid (B, T)
__global__ __launch_bounds__(256) void k_topk(const float* __restrict__ sim,
                                              int* __restrict__ idx_out) {
    int b = blockIdx.x;
    int t = blockIdx.y;
    int tid = threadIdx.x;
    const float* row = sim + ((size_t)t*B_ + b)*NLAB;
    float tv[8]; int ti[8];
#pragma unroll
    for (int k = 0; k < 8; ++k) { tv[k] = -3e38f; ti[k] = 0x7fffffff; }
    for (int n = tid; n < NLAB; n += 256) {
        float v = row[n];
        if (v > tv[7]) {
            tv[7] = v; ti[7] = n;
#pragma unroll
            for (int k = 7; k > 0; --k) {
                if (tv[k] > tv[k-1]) {
                    float fv = tv[k]; tv[k] = tv[k-1]; tv[k-1] = fv;
                    int fi = ti[k]; ti[k] = ti[k-1]; ti[k-1] = fi;
                }
            }
        }
    }
    __shared__ float sv[2048];
    __shared__ int   si[2048];
    __shared__ float pv[256];
    __shared__ int   pi[256];
    __shared__ int   pp[256];
#pragma unroll
    for (int k = 0; k < 8; ++k) { sv[tid*8+k] = tv[k]; si[tid*8+k] = ti[k]; }
    __syncthreads();
    for (int r = 0; r < 8; ++r) {
        float bv = -3e38f; int bi = 0x7fffffff; int bp = 0;
#pragma unroll
        for (int k = 0; k < 8; ++k) {
            int p = tid*8 + k;
            float v = sv[p]; int ii = si[p];
            if (v > bv || (v == bv && ii < bi)) { bv = v; bi = ii; bp = p; }
        }
        pv[tid] = bv; pi[tid] = bi; pp[tid] = bp;
        __syncthreads();
        for (int off = 128; off > 0; off >>= 1) {
            if (tid < off) {
                if (pv[tid+off] > pv[tid] || (pv[tid+off] == pv[tid] && pi[tid+off] < pi[tid])) {
                    pv[tid] = pv[tid+off]; pi[tid] = pi[tid+off]; pp[tid] = pp[tid+off];
                }
            }
            __syncthreads();
        }
        if (tid == 0) {
            idx_out[((size_t)b*T_ + t)*K_ + r] = pi[0];
            sv[pp[0]] = -3e38f;
        }
        __syncthreads();
    }
}

// build tokens: toks[(bt*9 + l)*769 + :]
__global__ __launch_bounds__(256) void k_toks(const float* __restrict__ lab_e,
                                              const float* __restrict__ lab_t,
                                              const float* __restrict__ uc,
                                              const int* __restrict__ idx,
                                              float* __restrict__ toks) {
    int g = blockIdx.x;            // 0..NROW-1
    int bt = g / L_, l = g % L_;
    int b = bt / T_, t = bt % T_;
    float* out = toks + (size_t)g*(D_+1);
    if (l < K_) {
        int n = idx[(size_t)bt*K_ + l];
        for (int d = threadIdx.x; d < D_; d += 256) {
            size_t base = (size_t)n*(3*D_) + d;
            out[d] = (lab_e[base] + lab_e[base + D_] + lab_e[base + 2*D_]) * (1.f/3.f);
        }
        if (threadIdx.x == 0) out[D_] = lab_t[(size_t)n*T_ + t];
    } else {
        for (int d = threadIdx.x; d < D_; d += 256)
            out[d] = uc[(size_t)b*D_ + d];
        if (threadIdx.x == 0) out[D_] = 0.f;
    }
}

// generic tiled fp32 GEMM: C(MxN) (+)= A(MxK) * B(KxN) (+ bias)
// BM=BN=64, BK=16, 256 threads, 4x4 microtile (round-2 known-good config)
template<bool ADD, bool BIAS>
__global__ __launch_bounds__(256) void k_sgemm(const float* __restrict__ A,
                                               const float* __restrict__ Bm,
                                               const float* __restrict__ bias,
                                               float* __restrict__ C,
                                               int M, int N, int Kd) {
    __shared__ float As[16][68];
    __shared__ float Bs[16][68];
    int bn = blockIdx.x * 64;
    int bm = blockIdx.y * 64;
    int tid = threadIdx.x;
    int tx = tid & 15, ty = tid >> 4;
    float acc[4][4] = {};
    int kc = tid & 15;
    int r0 = tid >> 4;
    int nn0 = tid & 63;
    int kk0 = tid >> 6;
    for (int k0 = 0; k0 < Kd; k0 += 16) {
        bool kok = (k0 + kc) < Kd;
#pragma unroll
        for (int rr = 0; rr < 4; ++rr) {
            int r = r0 + rr*16;
            int gm = bm + r;
            As[kc][r] = (kok && gm < M) ? A[(size_t)gm*Kd + k0 + kc] : 0.f;
        }
#pragma unroll
        for (int kki = 0; kki < 4; ++kki) {
            int kk = kk0 + kki*4;
            int gk = k0 + kk, gn = bn + nn0;
            Bs[kk][nn0] = (gk < Kd && gn < N) ? Bm[(size_t)gk*N + gn] : 0.f;
        }
        __syncthreads();
#pragma unroll
        for (int k = 0; k < 16; ++k) {
            float ar[4], br[4];
#pragma unroll
            for (int i = 0; i < 4; ++i) ar[i] = As[k][ty*4 + i];
#pragma unroll
            for (int j = 0; j < 4; ++j) br[j] = Bs[k][tx*4 + j];
#pragma unroll
            for (int i = 0; i < 4; ++i)
#pragma unroll
                for (int j = 0; j < 4; ++j)
                    acc[i][j] = fmaf(ar[i], br[j], acc[i][j]);
        }
        __syncthreads();
    }
#pragma unroll
    for (int i = 0; i < 4; ++i) {
        int gm = bm + ty*4 + i;
        if (gm >= M) continue;
#pragma unroll
        for (int j = 0; j < 4; ++j) {
            int gn = bn + tx*4 + j;
            if (gn >= N) continue;
            float v = acc[i][j];
            if (BIAS) v += bias[gn];
            size_t o = (size_t)gm*N + gn;
            if (ADD) C[o] += v; else C[o] = v;
        }
    }
}

// layer norm per row of H=256
__global__ __launch_bounds__(256) void k_ln(const float* __restrict__ x,
                                            const float* __restrict__ g,
                                            const float* __restrict__ b,
                                            float* __restrict__ xn) {
    int row = blockIdx.x, tid = threadIdx.x;
    float v = x[(size_t)row*H_ + tid];
    float mean = block_reduce_sum(v) * (1.f/H_);
    float d = v - mean;
    float var = block_reduce_sum(d*d) * (1.f/H_);
    xn[(size_t)row*H_ + tid] = d * rsqrtf(var + 1e-5f) * g[tid] + b[tid];
}

// causal depthwise conv (KC=4) + silu ; xc from first half of xz
__global__ __launch_bounds__(256) void k_conv(const float* __restrict__ xz,
                                              const float* __restrict__ cw,
                                              const float* __restrict__ cb,
                                              float* __restrict__ xc2) {
    int gid = blockIdx.x*256 + threadIdx.x;
    if (gid >= NBT*DI_) return;
    int n = gid / DI_, d = gid % DI_;
    float w0 = cw[d*4+0], w1 = cw[d*4+1], w2 = cw[d*4+2], w3 = cw[d*4+3];
    float bb = cb[d];
    const float* src = xz + (size_t)n*L_*(2*DI_) + d;
    float* dst = xc2 + (size_t)n*L_*DI_ + d;
    float x0 = 0.f, x1 = 0.f, x2 = 0.f;
#pragma unroll
    for (int l = 0; l < L_; ++l) {
        float x3 = src[(size_t)l*(2*DI_)];
        float s = bb + w0*x0 + w1*x1 + w2*x2 + w3*x3;
        dst[(size_t)l*DI_] = siluf_(s);
        x0 = x1; x1 = x2; x2 = x3;
    }
}

// dbl = xc2 @ Wx  (NROW x 48)
__global__ __launch_bounds__(256) void k_dbl(const float* __restrict__ xc2,
                                             const float* __restrict__ Wx,
                                             float* __restrict__ dbl) {
    int gid = blockIdx.x*256 + threadIdx.x;
    if (gid >= NROW*48) return;
    int row = gid / 48, j = gid % 48;
    const float* a = xc2 + (size_t)row*DI_;
    float s0 = 0.f, s1 = 0.f, s2 = 0.f, s3 = 0.f;
    for (int k = 0; k < DI_; k += 4) {
        s0 = fmaf(a[k+0], Wx[(size_t)(k+0)*48 + j], s0);
        s1 = fmaf(a[k+1], Wx[(size_t)(k+1)*48 + j], s1);
        s2 = fmaf(a[k+2], Wx[(size_t)(k+2)*48 + j], s2);
        s3 = fmaf(a[k+3], Wx[(size_t)(k+3)*48 + j], s3);
    }
    dbl[gid] = ((s0 + s1) + (s2 + s3));
}

// dt = softplus(dbl[:, :16] @ Wdt + bdt)   (NROW x 512)
__global__ __launch_bounds__(256) void k_dt(const float* __restrict__ dbl,
                                            const float* __restrict__ Wdt,
                                            const float* __restrict__ bdt,
                                            float* __restrict__ dt) {
    int gid = blockIdx.x*256 + threadIdx.x;
    if (gid >= NROW*DI_) return;
    int row = gid >> 9, d = gid & (DI_-1);
    const float* p = dbl + (size_t)row*48;
    float s = bdt[d];
#pragma unroll
    for (int r = 0; r < R_; ++r) s = fmaf(p[r], Wdt[(size_t)r*DI_ + d], s);
    dt[gid] = softplusf_(s);
}

// selective scan + skip + gate: y[row,d] = (sum_s hs*Cm + Dp*xc) * silu(z)
__global__ __launch_bounds__(256) void k_scan(const float* __restrict__ dtb,
                                              const float* __restrict__ xc2,
                                              const float* __restrict__ xz,
                                              const float* __restrict__ dbl,
                                              const float* __restrict__ A_log,
                                              const float* __restrict__ Dp,
                                              float* __restrict__ y) {
    int gid = blockIdx.x*256 + threadIdx.x;
    if (gid >= NBT*DI_) return;
    int n = gid >> 9, d = gid & (DI_-1);
    float a[S_];
#pragma unroll
    for (int s = 0; s < S_; ++s) a[s] = -expf(A_log[(size_t)d*S_ + s]);
    float dp = Dp[d];
    float h[S_];
#pragma unroll
    for (int s = 0; s < S_; ++s) h[s] = 0.f;
    for (int l = 0; l < L_; ++l) {
        size_t row = (size_t)n*L_ + l;
        float dtv = dtb[row*DI_ + d];
        float xcv = xc2[row*DI_ + d];
        float zv  = xz[row*(2*DI_) + DI_ + d];
        const float* q = dbl + row*48;
        float accv = 0.f;
#pragma unroll
        for (int s = 0; s < S_; ++s) {
            float Bv = q[16 + s], Cv = q[32 + s];
            h[s] = expf(dtv*a[s])*h[s] + dtv*Bv*xcv;
            accv = fmaf(h[s], Cv, accv);
        }
        y[row*DI_ + d] = (accv + dp*xcv) * siluf_(zv);
    }
}

// head: out[n] = relu(x[n,8,:] @ W1 + b1) @ W2 + b2
__global__ __launch_bounds__(128) void k_head(const float* __restrict__ x,
                                              const float* __restrict__ W1,
                                              const float* __restrict__ b1,
                                              const float* __restrict__ W2,
                                              const float* __restrict__ b2,
                                              float* __restrict__ out) {
    int n = blockIdx.x, tid = threadIdx.x;
    __shared__ float ms[H_];
    const float* src = x + ((size_t)n*L_ + (L_-1))*H_;
    ms[tid] = src[tid];
    ms[tid+128] = src[tid+128];
    __syncthreads();
    float s = b1[tid];
#pragma unroll 8
    for (int k = 0; k < H_; ++k) s = fmaf(ms[k], W1[(size_t)k*128 + tid], s);
    float h = fmaxf(s, 0.f);
    float p = h * W2[tid];
    float tot = block_reduce_sum(p);
    if (tid == 0) out[n] = tot + b2[0];
}

// ---------------- launch ----------------

extern "C" void kernel_launch(void* const* d_in, const int* in_sizes, int n_in,
                              void* d_out, int out_size, void* d_ws, size_t ws_size,
                              hipStream_t stream) {
    const float* unl   = (const float*)d_in[0];
    const float* lab_e = (const float*)d_in[1];
    const float* lab_t = (const float*)d_in[2];
    const float* mlog  = (const float*)d_in[3];
    const float* Wp    = (const float*)d_in[4];
    const float* bp    = (const float*)d_in[5];
    const float* ln_g  = (const float*)d_in[6];
    const float* ln_b  = (const float*)d_in[7];
    const float* Win   = (const float*)d_in[8];
    const float* conv_w= (const float*)d_in[9];
    const float* conv_b= (const float*)d_in[10];
    const float* Wx    = (const float*)d_in[11];
    const float* Wdt   = (const float*)d_in[12];
    const float* bdt   = (const float*)d_in[13];
    const float* A_log = (const float*)d_in[14];
    const float* Dp    = (const float*)d_in[15];
    const float* Wout  = (const float*)d_in[16];
    const float* W1    = (const float*)d_in[17];
    const float* b1    = (const float*)d_in[18];
    const float* W2    = (const float*)d_in[19];
    const float* b2    = (const float*)d_in[20];

    float* ws   = (float*)d_ws;
    float* w    = ws;                          // 16
    int*   idx  = (int*)(ws + 16);             // 10240
    float* uc   = ws + 16 + 10240;             // B*D = 196608
    float* base = uc + (size_t)B_*D_;
    // phase 1 (overlaps phase 2 region)
    float* qn   = base;                        // T*B*D = 983040
    float* rn   = qn + (size_t)T_*B_*D_;       // NLAB*T = 100000
    float* sim  = rn + (size_t)NLAB*T_;        // T*B*NLAB = 25,600,000
    // phase 2
    float* toks = base;                        // NROW*769
    float* xa   = toks + (size_t)NROW*(D_+1);  // NROW*256
    float* xb   = xa + (size_t)NROW*H_;        // NROW*256
    float* xz   = xb + (size_t)NROW*H_;        // NROW*1024
    float* xc2  = xz + (size_t)NROW*(2*DI_);   // NROW*512
    float* dbl  = xc2 + (size_t)NROW*DI_;      // NROW*48
    float* dtb  = dbl + (size_t)NROW*48;       // NROW*512
    float* y    = dtb + (size_t)NROW*DI_;      // NROW*512

    k_softmax_w<<<1, 64, 0, stream>>>(mlog, w);
    k_qn_uc<<<B_, 256, 0, stream>>>(unl, w, qn, uc);
    k_rn<<<NLAB, 256, 0, stream>>>(lab_e, w, rn);
    {
        dim3 g(T_*2, (NLAB + 127) / 128);
        k_simf<<<g, 256, 0, stream>>>(qn, lab_e, w, rn, sim);
    }
    {
        dim3 g(B_, T_);
        k_topk<<<g, 256, 0, stream>>>(sim, idx);
    }
    k_toks<<<NROW, 256, 0, stream>>>(lab_e, lab_t, uc, idx, toks);
    {
        dim3 g(H_/64, NROW/64);
        k_sgemm<false,true><<<g, 256, 0, stream>>>(toks, Wp, bp, xa, NROW, H_, D_+1);
    }
    // reference's residual is around the POST-LN tensor:
    //   xn = LN(x); x = xn + f(xn) @ Wout   (pre-norm x is discarded)
    float* cur = xa;
    float* oth = xb;
    for (int i = 0; i < NL_; ++i) {
        k_ln<<<NROW, 256, 0, stream>>>(cur, ln_g + (size_t)i*H_, ln_b + (size_t)i*H_, oth);
        {
            dim3 g((2*DI_)/64, NROW/64);
            k_sgemm<false,false><<<g, 256, 0, stream>>>(oth, Win + (size_t)i*H_*(2*DI_), nullptr, xz, NROW, 2*DI_, H_);
        }
        k_conv<<<(NBT*DI_ + 255)/256, 256, 0, stream>>>(xz, conv_w + (size_t)i*DI_*KC_, conv_b + (size_t)i*DI_, xc2);
        k_dbl<<<(NROW*48 + 255)/256, 256, 0, stream>>>(xc2, Wx + (size_t)i*DI_*48, dbl);
        k_dt<<<(NROW*DI_ + 255)/256, 256, 0, stream>>>(dbl, Wdt + (size_t)i*R_*DI_, bdt + (size_t)i*DI_, dtb);
        k_scan<<<(NBT*DI_ + 255)/256, 256, 0, stream>>>(dtb, xc2, xz, dbl, A_log + (size_t)i*DI_*S_, Dp + (size_t)i*DI_, y);
        {
            dim3 g(H_/64, NROW/64);
            k_sgemm<true,false><<<g, 256, 0, stream>>>(y, Wout + (size_t)i*DI_*H_, nullptr, oth, NROW, H_, DI_);
        }
        float* tmp = cur; cur = oth; oth = tmp;
    }
    k_head<<<NBT, 128, 0, stream>>>(cur, W1, b1, W2, b2, (float*)d_out);
}

// Round 5
// 1880.496 us; speedup vs baseline: 2.0128x; 1.4066x over previous
//
#include <hip/hip_runtime.h>
#include <math.h>

#define B_   256
#define NLAB 20000
#define M_   3
#define D_   768
#define T_   5
#define K_   8
#define H_   256
#define DI_  512
#define S_   16
#define R_   16
#define NL_  4
#define KC_  4
#define L_   9          // K+1 tokens
#define NBT  1280       // B*T sequences
#define NROW 11520      // NBT*L flattened rows

typedef __attribute__((ext_vector_type(8))) short bf16x8;
typedef __attribute__((ext_vector_type(4))) float floatx4;

// ---------------- helpers ----------------

__device__ __forceinline__ float block_reduce_sum(float v) {
    __shared__ float red[4];
    int lane = threadIdx.x & 63;
    int wid  = threadIdx.x >> 6;
#pragma unroll
    for (int o = 32; o > 0; o >>= 1) v += __shfl_down(v, o);
    if (lane == 0) red[wid] = v;
    __syncthreads();
    int nw = (int)(blockDim.x >> 6);
    float r = 0.f;
#pragma unroll
    for (int i = 0; i < 4; ++i) if (i < nw) r += red[i];
    __syncthreads();
    return r;
}

__device__ __forceinline__ float sigmoidf_(float x) { return 1.f / (1.f + expf(-x)); }
__device__ __forceinline__ float siluf_(float x)    { return x * sigmoidf_(x); }
__device__ __forceinline__ float softplusf_(float x){ return x > 20.f ? x : log1pf(expf(x)); }

// round-to-nearest-even fp32 -> bf16 bits
__device__ __forceinline__ unsigned short f2bf(float x) {
    unsigned u = __float_as_uint(x);
    unsigned r = (u + 0x7fffu + ((u >> 16) & 1u)) >> 16;
    return (unsigned short)r;
}
__device__ __forceinline__ float bf2f(unsigned short h) {
    return __uint_as_float(((unsigned)h) << 16);
}

// ---------------- kernels ----------------

__global__ void k_softmax_w(const float* __restrict__ mlog, float* __restrict__ w) {
    int t = threadIdx.x;
    if (t < T_) {
        float a = mlog[t*M_+0], b = mlog[t*M_+1], c = mlog[t*M_+2];
        float mx = fmaxf(a, fmaxf(b, c));
        float ea = expf(a-mx), eb = expf(b-mx), ec = expf(c-mx);
        float s = ea + eb + ec;
        w[t*M_+0] = ea/s; w[t*M_+1] = eb/s; w[t*M_+2] = ec/s;
    }
}

// qn (normalized queries) -> bf16 hi/lo planes ; uc = mean over m
__global__ __launch_bounds__(256) void k_qn_uc(const float* __restrict__ unl,
                                               const float* __restrict__ w,
                                               unsigned short* __restrict__ qnh,
                                               unsigned short* __restrict__ qnl,
                                               float* __restrict__ uc) {
    int b = blockIdx.x, tid = threadIdx.x;
    float e[3][3];
#pragma unroll
    for (int c = 0; c < 3; ++c) {
        int d = tid + c*256;
#pragma unroll
        for (int m = 0; m < 3; ++m)
            e[c][m] = unl[((size_t)b*3 + m)*D_ + d];
    }
#pragma unroll
    for (int c = 0; c < 3; ++c)
        uc[(size_t)b*D_ + tid + c*256] = (e[c][0] + e[c][1] + e[c][2]) * (1.f/3.f);
    for (int t = 0; t < T_; ++t) {
        float w0 = w[t*3+0], w1 = w[t*3+1], w2 = w[t*3+2];
        float q[3]; float ss = 0.f;
#pragma unroll
        for (int c = 0; c < 3; ++c) {
            q[c] = w0*e[c][0] + w1*e[c][1] + w2*e[c][2];
            ss += q[c]*q[c];
        }
        float tot = block_reduce_sum(ss);
        float inv = rsqrtf(tot + 1e-8f);
#pragma unroll
        for (int c = 0; c < 3; ++c) {
            float v = q[c]*inv;
            size_t o = ((size_t)t*B_ + b)*D_ + tid + c*256;
            unsigned short h = f2bf(v);
            qnh[o] = h; qnl[o] = f2bf(v - bf2f(h));
        }
    }
}

__global__ __launch_bounds__(256) void k_rn(const float* __restrict__ lab_e,
                                            const float* __restrict__ w,
                                            float* __restrict__ rn) {
    int n = blockIdx.x, tid = threadIdx.x;
    float e[3][3];
#pragma unroll
    for (int c = 0; c < 3; ++c) {
        int d = tid + c*256;
#pragma unroll
        for (int m = 0; m < 3; ++m)
            e[c][m] = lab_e[((size_t)n*3 + m)*D_ + d];
    }
    for (int t = 0; t < T_; ++t) {
        float w0 = w[t*3+0], w1 = w[t*3+1], w2 = w[t*3+2];
        float ss = 0.f;
#pragma unroll
        for (int c = 0; c < 3; ++c) {
            float q = w0*e[c][0] + w1*e[c][1] + w2*e[c][2];
            ss += q*q;
        }
        float tot = block_reduce_sum(ss);
        if (tid == 0) rn[(size_t)n*T_ + t] = rsqrtf(tot + 1e-8f);
    }
}

// split-bf16 MFMA sim GEMM, BM=256 (all b), BN=128, BK=32; 512 threads / 8 waves
// grid (T_, ceil(NLAB/128))
__global__ __launch_bounds__(512) void k_simf(const unsigned short* __restrict__ qnh,
                                              const unsigned short* __restrict__ qnl,
                                              const float* __restrict__ lab_e,
                                              const float* __restrict__ w,
                                              const float* __restrict__ rn,
                                              float* __restrict__ sim) {
    __shared__ unsigned short Ah[256*40], Al[256*40], Bh[128*40], Bl[128*40];
    int t  = blockIdx.x;
    int bn = blockIdx.y * 128;
    float w0 = w[t*3+0], w1 = w[t*3+1], w2 = w[t*3+2];
    int tid = threadIdx.x;
    int lane = tid & 63, wv = tid >> 6;
    int mbase = (wv >> 1)*64, nbase = (wv & 1)*64;
    int fr = lane & 15, kg = lane >> 4;
    floatx4 acc[4][4];
#pragma unroll
    for (int mi = 0; mi < 4; ++mi)
#pragma unroll
        for (int ni = 0; ni < 4; ++ni)
            acc[mi][ni] = (floatx4){0.f, 0.f, 0.f, 0.f};

    for (int k0 = 0; k0 < D_; k0 += 32) {
        // A: pure copy of pre-converted qn planes (256 x 32)
#pragma unroll
        for (int f = 0; f < 2; ++f) {
            int v = f*512 + tid;
            int r = v >> 2, kq = v & 3;
            size_t g = ((size_t)t*B_ + r)*D_ + k0 + kq*8;
            int off = r*40 + kq*8;
            *(int4*)(Ah + off) = *(const int4*)(qnh + g);
            *(int4*)(Al + off) = *(const int4*)(qnl + g);
        }
        // B: weighted lab_e -> hi/lo (128 x 32), converted exactly once per element
#pragma unroll
        for (int f = 0; f < 2; ++f) {
            int v = f*512 + tid;
            int r = v >> 3, kq = v & 7;
            int gn = bn + r;
            float4 s = make_float4(0.f, 0.f, 0.f, 0.f);
            if (gn < NLAB) {
                const float* bp = lab_e + (size_t)gn*(3*D_) + k0 + kq*4;
                float4 e0 = *(const float4*)(bp);
                float4 e1 = *(const float4*)(bp + D_);
                float4 e2 = *(const float4*)(bp + 2*D_);
                s.x = w0*e0.x + w1*e1.x + w2*e2.x;
                s.y = w0*e0.y + w1*e1.y + w2*e2.y;
                s.z = w0*e0.z + w1*e1.z + w2*e2.z;
                s.w = w0*e0.w + w1*e1.w + w2*e2.w;
            }
            ushort4 h, l;
            h.x = f2bf(s.x); l.x = f2bf(s.x - bf2f(h.x));
            h.y = f2bf(s.y); l.y = f2bf(s.y - bf2f(h.y));
            h.z = f2bf(s.z); l.z = f2bf(s.z - bf2f(h.z));
            h.w = f2bf(s.w); l.w = f2bf(s.w - bf2f(h.w));
            int off = r*40 + kq*4;
            *(ushort4*)(Bh + off) = h;
            *(ushort4*)(Bl + off) = l;
        }
        __syncthreads();

        bf16x8 bhf[4], blf[4];
#pragma unroll
        for (int ni = 0; ni < 4; ++ni) {
            int off = (nbase + ni*16 + fr)*40 + kg*8;
            bhf[ni] = *(const bf16x8*)(Bh + off);
            blf[ni] = *(const bf16x8*)(Bl + off);
        }
#pragma unroll
        for (int mi = 0; mi < 4; ++mi) {
            int off = (mbase + mi*16 + fr)*40 + kg*8;
            bf16x8 ahf = *(const bf16x8*)(Ah + off);
            bf16x8 alf = *(const bf16x8*)(Al + off);
#pragma unroll
            for (int ni = 0; ni < 4; ++ni) {
                floatx4 c = acc[mi][ni];
                c = __builtin_amdgcn_mfma_f32_16x16x32_bf16(ahf, bhf[ni], c, 0, 0, 0);
                c = __builtin_amdgcn_mfma_f32_16x16x32_bf16(alf, bhf[ni], c, 0, 0, 0);
                c = __builtin_amdgcn_mfma_f32_16x16x32_bf16(ahf, blf[ni], c, 0, 0, 0);
                acc[mi][ni] = c;
            }
        }
        __syncthreads();
    }
    float* st = sim + (size_t)t*B_*NLAB;
#pragma unroll
    for (int mi = 0; mi < 4; ++mi) {
        int m = mbase + mi*16 + kg*4;
#pragma unroll
        for (int ni = 0; ni < 4; ++ni) {
            int n = bn + nbase + ni*16 + fr;
            if (n < NLAB) {
                float rv = rn[(size_t)n*T_ + t];
#pragma unroll
                for (int r = 0; r < 4; ++r)
                    st[(size_t)(m + r)*NLAB + n] = acc[mi][ni][r] * rv;
            }
        }
    }
}

// per-row top-8, grid (B, T)
__global__ __launch_bounds__(256) void k_topk(const float* __restrict__ sim,
                                              int* __restrict__ idx_out) {
    int b = blockIdx.x;
    int t = blockIdx.y;
    int tid = threadIdx.x;
    const float* row = sim + ((size_t)t*B_ + b)*NLAB;
    float tv[8]; int ti[8];
#pragma unroll
    for (int k = 0; k < 8; ++k) { tv[k] = -3e38f; ti[k] = 0x7fffffff; }
    for (int n = tid; n < NLAB; n += 256) {
        float v = row[n];
        if (v > tv[7]) {
            tv[7] = v; ti[7] = n;
#pragma unroll
            for (int k = 7; k > 0; --k) {
                if (tv[k] > tv[k-1]) {
                    float fv = tv[k]; tv[k] = tv[k-1]; tv[k-1] = fv;
                    int fi = ti[k]; ti[k] = ti[k-1]; ti[k-1] = fi;
                }
            }
        }
    }
    __shared__ float sv[2048];
    __shared__ int   si[2048];
    __shared__ float pv[256];
    __shared__ int   pi[256];
    __shared__ int   pp[256];
#pragma unroll
    for (int k = 0; k < 8; ++k) { sv[tid*8+k] = tv[k]; si[tid*8+k] = ti[k]; }
    __syncthreads();
    for (int r = 0; r < 8; ++r) {
        float bv = -3e38f; int bi = 0x7fffffff; int bp = 0;
#pragma unroll
        for (int k = 0; k < 8; ++k) {
            int p = tid*8 + k;
            float v = sv[p]; int ii = si[p];
            if (v > bv || (v == bv && ii < bi)) { bv = v; bi = ii; bp = p; }
        }
        pv[tid] = bv; pi[tid] = bi; pp[tid] = bp;
        __syncthreads();
        for (int off = 128; off > 0; off >>= 1) {
            if (tid < off) {
                if (pv[tid+off] > pv[tid] || (pv[tid+off] == pv[tid] && pi[tid+off] < pi[tid])) {
                    pv[tid] = pv[tid+off]; pi[tid] = pi[tid+off]; pp[tid] = pp[tid+off];
                }
            }
            __syncthreads();
        }
        if (tid == 0) {
            idx_out[((size_t)b*T_ + t)*K_ + r] = pi[0];
            sv[pp[0]] = -3e38f;
        }
        __syncthreads();
    }
}

// build token planes (bf16 hi/lo, 768 cols) + trait vector tt
__global__ __launch_bounds__(256) void k_toks(const float* __restrict__ lab_e,
                                              const float* __restrict__ lab_t,
                                              const float* __restrict__ uc,
                                              const int* __restrict__ idx,
                                              unsigned short* __restrict__ tokh,
                                              unsigned short* __restrict__ tokl,
                                              float* __restrict__ tt) {
    int g = blockIdx.x;            // 0..NROW-1
    int bt = g / L_, l = g % L_;
    int b = bt / T_, t = bt % T_;
    size_t ro = (size_t)g*D_;
    if (l < K_) {
        int n = idx[(size_t)bt*K_ + l];
        for (int d = threadIdx.x; d < D_; d += 256) {
            size_t base = (size_t)n*(3*D_) + d;
            float v = (lab_e[base] + lab_e[base + D_] + lab_e[base + 2*D_]) * (1.f/3.f);
            unsigned short h = f2bf(v);
            tokh[ro + d] = h; tokl[ro + d] = f2bf(v - bf2f(h));
        }
        if (threadIdx.x == 0) tt[g] = lab_t[(size_t)n*T_ + t];
    } else {
        for (int d = threadIdx.x; d < D_; d += 256) {
            float v = uc[(size_t)b*D_ + d];
            unsigned short h = f2bf(v);
            tokh[ro + d] = h; tokl[ro + d] = f2bf(v - bf2f(h));
        }
        if (threadIdx.x == 0) tt[g] = 0.f;
    }
}

// convert+transpose weight K x N -> hi/lo planes [n][k]
__global__ void k_cvtw(const float* __restrict__ W,
                       unsigned short* __restrict__ th,
                       unsigned short* __restrict__ tl,
                       int Kd, int N) {
    int total = Kd * N;
    for (int id = blockIdx.x*256 + threadIdx.x; id < total; id += gridDim.x*256) {
        int n = id / Kd, k = id - n*Kd;
        float v = W[(size_t)k*N + n];
        unsigned short h = f2bf(v);
        th[id] = h; tl[id] = f2bf(v - bf2f(h));
    }
}

// split-bf16 MFMA GEMM from pre-converted planes.
// A: M x Kd (hi/lo), B(transposed): N x Kd (hi/lo), C: M x N fp32.
// BM=128, BN=64, BK=32; 256 threads / 4 waves, wave = 64x32 (4x2 frags)
template<bool ADD, bool BIAS, bool TRAIT>
__global__ __launch_bounds__(256) void k_mgemm(const unsigned short* __restrict__ ah,
                                               const unsigned short* __restrict__ al,
                                               const unsigned short* __restrict__ bh,
                                               const unsigned short* __restrict__ bl,
                                               const float* __restrict__ bias,
                                               const float* __restrict__ wtrait,
                                               const float* __restrict__ tt,
                                               float* __restrict__ C,
                                               int N, int Kd) {
    __shared__ unsigned short Ah[128*40], Al[128*40], Bh[64*40], Bl[64*40];
    int bn = blockIdx.x * 64;
    int bm = blockIdx.y * 128;
    int tid = threadIdx.x;
    int lane = tid & 63, wv = tid >> 6;
    int mbase = (wv >> 1)*64, nbase = (wv & 1)*32;
    int fr = lane & 15, kg = lane >> 4;
    floatx4 acc[4][2];
#pragma unroll
    for (int mi = 0; mi < 4; ++mi)
#pragma unroll
        for (int ni = 0; ni < 2; ++ni)
            acc[mi][ni] = (floatx4){0.f, 0.f, 0.f, 0.f};

    for (int k0 = 0; k0 < Kd; k0 += 32) {
#pragma unroll
        for (int f = 0; f < 2; ++f) {
            int v = f*256 + tid;
            int r = v >> 2, kq = v & 3;
            size_t g = (size_t)(bm + r)*Kd + k0 + kq*8;
            int off = r*40 + kq*8;
            *(int4*)(Ah + off) = *(const int4*)(ah + g);
            *(int4*)(Al + off) = *(const int4*)(al + g);
        }
        {
            int r = tid >> 2, kq = tid & 3;
            size_t g = (size_t)(bn + r)*Kd + k0 + kq*8;
            int off = r*40 + kq*8;
            *(int4*)(Bh + off) = *(const int4*)(bh + g);
            *(int4*)(Bl + off) = *(const int4*)(bl + g);
        }
        __syncthreads();

        bf16x8 bhf[2], blf[2];
#pragma unroll
        for (int ni = 0; ni < 2; ++ni) {
            int off = (nbase + ni*16 + fr)*40 + kg*8;
            bhf[ni] = *(const bf16x8*)(Bh + off);
            blf[ni] = *(const bf16x8*)(Bl + off);
        }
#pragma unroll
        for (int mi = 0; mi < 4; ++mi) {
            int off = (mbase + mi*16 + fr)*40 + kg*8;
            bf16x8 ahf = *(const bf16x8*)(Ah + off);
            bf16x8 alf = *(const bf16x8*)(Al + off);
#pragma unroll
            for (int ni = 0; ni < 2; ++ni) {
                floatx4 c = acc[mi][ni];
                c = __builtin_amdgcn_mfma_f32_16x16x32_bf16(ahf, bhf[ni], c, 0, 0, 0);
                c = __builtin_amdgcn_mfma_f32_16x16x32_bf16(alf, bhf[ni], c, 0, 0, 0);
                c = __builtin_amdgcn_mfma_f32_16x16x32_bf16(ahf, blf[ni], c, 0, 0, 0);
                acc[mi][ni] = c;
            }
        }
        __syncthreads();
    }
#pragma unroll
    for (int mi = 0; mi < 4; ++mi) {
        int m0 = bm + mbase + mi*16 + kg*4;
#pragma unroll
        for (int ni = 0; ni < 2; ++ni) {
            int n = bn + nbase + ni*16 + fr;
#pragma unroll
            for (int r = 0; r < 4; ++r) {
                float v = acc[mi][ni][r];
                if (TRAIT) v += tt[m0 + r] * wtrait[n];
                if (BIAS)  v += bias[n];
                size_t o = (size_t)(m0 + r)*N + n;
                if (ADD) C[o] += v; else C[o] = v;
            }
        }
    }
}

// layer norm -> fp32 out + bf16 hi/lo planes
__global__ __launch_bounds__(256) void k_ln(const float* __restrict__ x,
                                            const float* __restrict__ g,
                                            const float* __restrict__ b,
                                            float* __restrict__ xn,
                                            unsigned short* __restrict__ xnh,
                                            unsigned short* __restrict__ xnl) {
    int row = blockIdx.x, tid = threadIdx.x;
    float v = x[(size_t)row*H_ + tid];
    float mean = block_reduce_sum(v) * (1.f/H_);
    float d = v - mean;
    float var = block_reduce_sum(d*d) * (1.f/H_);
    float o = d * rsqrtf(var + 1e-5f) * g[tid] + b[tid];
    size_t oo = (size_t)row*H_ + tid;
    xn[oo] = o;
    unsigned short h = f2bf(o);
    xnh[oo] = h; xnl[oo] = f2bf(o - bf2f(h));
}

// causal depthwise conv (KC=4) + silu
__global__ __launch_bounds__(256) void k_conv(const float* __restrict__ xz,
                                              const float* __restrict__ cw,
                                              const float* __restrict__ cb,
                                              float* __restrict__ xc2) {
    int gid = blockIdx.x*256 + threadIdx.x;
    if (gid >= NBT*DI_) return;
    int n = gid / DI_, d = gid % DI_;
    float w0 = cw[d*4+0], w1 = cw[d*4+1], w2 = cw[d*4+2], w3 = cw[d*4+3];
    float bb = cb[d];
    const float* src = xz + (size_t)n*L_*(2*DI_) + d;
    float* dst = xc2 + (size_t)n*L_*DI_ + d;
    float x0 = 0.f, x1 = 0.f, x2 = 0.f;
#pragma unroll
    for (int l = 0; l < L_; ++l) {
        float x3 = src[(size_t)l*(2*DI_)];
        float s = bb + w0*x0 + w1*x1 + w2*x2 + w3*x3;
        dst[(size_t)l*DI_] = siluf_(s);
        x0 = x1; x1 = x2; x2 = x3;
    }
}

// dbl = xc2 @ Wx  (NROW x 48)
__global__ __launch_bounds__(256) void k_dbl(const float* __restrict__ xc2,
                                             const float* __restrict__ Wx,
                                             float* __restrict__ dbl) {
    int gid = blockIdx.x*256 + threadIdx.x;
    if (gid >= NROW*48) return;
    int row = gid / 48, j = gid % 48;
    const float* a = xc2 + (size_t)row*DI_;
    float s0 = 0.f, s1 = 0.f, s2 = 0.f, s3 = 0.f;
    for (int k = 0; k < DI_; k += 4) {
        s0 = fmaf(a[k+0], Wx[(size_t)(k+0)*48 + j], s0);
        s1 = fmaf(a[k+1], Wx[(size_t)(k+1)*48 + j], s1);
        s2 = fmaf(a[k+2], Wx[(size_t)(k+2)*48 + j], s2);
        s3 = fmaf(a[k+3], Wx[(size_t)(k+3)*48 + j], s3);
    }
    dbl[gid] = ((s0 + s1) + (s2 + s3));
}

// dt = softplus(dbl[:, :16] @ Wdt + bdt)
__global__ __launch_bounds__(256) void k_dt(const float* __restrict__ dbl,
                                            const float* __restrict__ Wdt,
                                            const float* __restrict__ bdt,
                                            float* __restrict__ dt) {
    int gid = blockIdx.x*256 + threadIdx.x;
    if (gid >= NROW*DI_) return;
    int row = gid >> 9, d = gid & (DI_-1);
    const float* p = dbl + (size_t)row*48;
    float s = bdt[d];
#pragma unroll
    for (int r = 0; r < R_; ++r) s = fmaf(p[r], Wdt[(size_t)r*DI_ + d], s);
    dt[gid] = softplusf_(s);
}

// selective scan + skip + gate -> y as bf16 hi/lo planes
__global__ __launch_bounds__(256) void k_scan(const float* __restrict__ dtb,
                                              const float* __restrict__ xc2,
                                              const float* __restrict__ xz,
                                              const float* __restrict__ dbl,
                                              const float* __restrict__ A_log,
                                              const float* __restrict__ Dp,
                                              unsigned short* __restrict__ yh,
                                              unsigned short* __restrict__ yl) {
    int gid = blockIdx.x*256 + threadIdx.x;
    if (gid >= NBT*DI_) return;
    int n = gid >> 9, d = gid & (DI_-1);
    float a[S_];
#pragma unroll
    for (int s = 0; s < S_; ++s) a[s] = -expf(A_log[(size_t)d*S_ + s]);
    float dp = Dp[d];
    float h[S_];
#pragma unroll
    for (int s = 0; s < S_; ++s) h[s] = 0.f;
    for (int l = 0; l < L_; ++l) {
        size_t row = (size_t)n*L_ + l;
        float dtv = dtb[row*DI_ + d];
        float xcv = xc2[row*DI_ + d];
        float zv  = xz[row*(2*DI_) + DI_ + d];
        const float* q = dbl + row*48;
        float accv = 0.f;
#pragma unroll
        for (int s = 0; s < S_; ++s) {
            float Bv = q[16 + s], Cv = q[32 + s];
            h[s] = expf(dtv*a[s])*h[s] + dtv*Bv*xcv;
            accv = fmaf(h[s], Cv, accv);
        }
        float yv = (accv + dp*xcv) * siluf_(zv);
        unsigned short hh = f2bf(yv);
        yh[row*DI_ + d] = hh;
        yl[row*DI_ + d] = f2bf(yv - bf2f(hh));
    }
}

// head
__global__ __launch_bounds__(128) void k_head(const float* __restrict__ x,
                                              const float* __restrict__ W1,
                                              const float* __restrict__ b1,
                                              const float* __restrict__ W2,
                                              const float* __restrict__ b2,
                                              float* __restrict__ out) {
    int n = blockIdx.x, tid = threadIdx.x;
    __shared__ float ms[H_];
    const float* src = x + ((size_t)n*L_ + (L_-1))*H_;
    ms[tid] = src[tid];
    ms[tid+128] = src[tid+128];
    __syncthreads();
    float s = b1[tid];
#pragma unroll 8
    for (int k = 0; k < H_; ++k) s = fmaf(ms[k], W1[(size_t)k*128 + tid], s);
    float h = fmaxf(s, 0.f);
    float p = h * W2[tid];
    float tot = block_reduce_sum(p);
    if (tid == 0) out[n] = tot + b2[0];
}

// ---------------- launch ----------------

extern "C" void kernel_launch(void* const* d_in, const int* in_sizes, int n_in,
                              void* d_out, int out_size, void* d_ws, size_t ws_size,
                              hipStream_t stream) {
    const float* unl   = (const float*)d_in[0];
    const float* lab_e = (const float*)d_in[1];
    const float* lab_t = (const float*)d_in[2];
    const float* mlog  = (const float*)d_in[3];
    const float* Wp    = (const float*)d_in[4];
    const float* bp    = (const float*)d_in[5];
    const float* ln_g  = (const float*)d_in[6];
    const float* ln_b  = (const float*)d_in[7];
    const float* Win   = (const float*)d_in[8];
    const float* conv_w= (const float*)d_in[9];
    const float* conv_b= (const float*)d_in[10];
    const float* Wx    = (const float*)d_in[11];
    const float* Wdt   = (const float*)d_in[12];
    const float* bdt   = (const float*)d_in[13];
    const float* A_log = (const float*)d_in[14];
    const float* Dp    = (const float*)d_in[15];
    const float* Wout  = (const float*)d_in[16];
    const float* W1    = (const float*)d_in[17];
    const float* b1    = (const float*)d_in[18];
    const float* W2    = (const float*)d_in[19];
    const float* b2    = (const float*)d_in[20];

    float* ws = (float*)d_ws;
    // fixed layout (float units); ushort buffers cast from 4-aligned float offsets
    float* w    = ws + 0;                                    // 16
    int*   idx  = (int*)(ws + 16);                           // 10240 ints
    float* uc   = ws + 10256;                                // 196,608
    float* rn   = ws + 206864;                               // 100,000
    float* tt   = ws + 306864;                               // 11,520
    unsigned short* qnh   = (unsigned short*)(ws + 318384);  // 983,040 ush
    unsigned short* qnl   = (unsigned short*)(ws + 809904);
    unsigned short* wph   = (unsigned short*)(ws + 1301424); // 196,608 ush
    unsigned short* wpl   = (unsigned short*)(ws + 1399728);
    unsigned short* winh  = (unsigned short*)(ws + 1498032); // 1,048,576 ush
    unsigned short* winl  = (unsigned short*)(ws + 2022320);
    unsigned short* wouth = (unsigned short*)(ws + 2546608); // 524,288 ush
    unsigned short* woutl = (unsigned short*)(ws + 2808752);
    float* xa   = ws + 3070896;                              // 2,949,120
    float* xb   = ws + 6020016;                              // 2,949,120
    unsigned short* xnh   = (unsigned short*)(ws + 8969136); // 2,949,120 ush
    unsigned short* xnl   = (unsigned short*)(ws + 10443696);
    float* xc2  = ws + 11918256;                             // 5,898,240
    float* dbl  = ws + 17816496;                             // 552,960
    float* simreg = ws + 18369456;                           // 25,600,000
    float* sim  = simreg;
    float* xz   = simreg;                                    // 11,796,480 (phase 2)
    float* dtb  = simreg + 11796480;                         // 5,898,240
    unsigned short* tokh = (unsigned short*)(simreg + 11796480); // 8,847,360 ush (dead before dtb used)
    unsigned short* tokl = (unsigned short*)(simreg + 16220160);
    unsigned short* yh   = (unsigned short*)(simreg + 17694720); // 5,898,240 ush
    unsigned short* yl   = (unsigned short*)(simreg + 20643840);

    k_softmax_w<<<1, 64, 0, stream>>>(mlog, w);
    k_qn_uc<<<B_, 256, 0, stream>>>(unl, w, qnh, qnl, uc);
    k_rn<<<NLAB, 256, 0, stream>>>(lab_e, w, rn);
    // weight conversions (once per call)
    k_cvtw<<<(768*256 + 255)/256, 256, 0, stream>>>(Wp, wph, wpl, 768, 256);
    for (int i = 0; i < NL_; ++i) {
        k_cvtw<<<(256*1024 + 255)/256, 256, 0, stream>>>(Win + (size_t)i*H_*(2*DI_),
                                                         winh + (size_t)i*H_*(2*DI_),
                                                         winl + (size_t)i*H_*(2*DI_), 256, 1024);
        k_cvtw<<<(512*256 + 255)/256, 256, 0, stream>>>(Wout + (size_t)i*DI_*H_,
                                                        wouth + (size_t)i*DI_*H_,
                                                        woutl + (size_t)i*DI_*H_, 512, 256);
    }
    {
        dim3 g(T_, (NLAB + 127) / 128);
        k_simf<<<g, 512, 0, stream>>>(qnh, qnl, lab_e, w, rn, sim);
    }
    {
        dim3 g(B_, T_);
        k_topk<<<g, 256, 0, stream>>>(sim, idx);
    }
    k_toks<<<NROW, 256, 0, stream>>>(lab_e, lab_t, uc, idx, tokh, tokl, tt);
    {
        dim3 g(H_/64, NROW/128);
        k_mgemm<false,true,true><<<g, 256, 0, stream>>>(tokh, tokl, wph, wpl,
                                                        bp, Wp + (size_t)768*H_, tt, xa, H_, D_);
    }
    float* cur = xa;
    float* oth = xb;
    for (int i = 0; i < NL_; ++i) {
        k_ln<<<NROW, 256, 0, stream>>>(cur, ln_g + (size_t)i*H_, ln_b + (size_t)i*H_, oth, xnh, xnl);
        {
            dim3 g((2*DI_)/64, NROW/128);
            k_mgemm<false,false,false><<<g, 256, 0, stream>>>(xnh, xnl,
                winh + (size_t)i*H_*(2*DI_), winl + (size_t)i*H_*(2*DI_),
                nullptr, nullptr, nullptr, xz, 2*DI_, H_);
        }
        k_conv<<<(NBT*DI_ + 255)/256, 256, 0, stream>>>(xz, conv_w + (size_t)i*DI_*KC_, conv_b + (size_t)i*DI_, xc2);
        k_dbl<<<(NROW*48 + 255)/256, 256, 0, stream>>>(xc2, Wx + (size_t)i*DI_*48, dbl);
        k_dt<<<(NROW*DI_ + 255)/256, 256, 0, stream>>>(dbl, Wdt + (size_t)i*R_*DI_, bdt + (size_t)i*DI_, dtb);
        k_scan<<<(NBT*DI_ + 255)/256, 256, 0, stream>>>(dtb, xc2, xz, dbl, A_log + (size_t)i*DI_*S_, Dp + (size_t)i*DI_, yh, yl);
        {
            dim3 g(H_/64, NROW/128);
            k_mgemm<true,false,false><<<g, 256, 0, stream>>>(yh, yl,
                wouth + (size_t)i*DI_*H_, woutl + (size_t)i*DI_*H_,
                nullptr, nullptr, nullptr, oth, H_, DI_);
        }
        float* tmp = cur; cur = oth; oth = tmp;
    }
    k_head<<<NBT, 128, 0, stream>>>(cur, W1, b1, W2, b2, (float*)d_out);
}